// Round 1
// 269.631 us; speedup vs baseline: 1.0732x; 1.0732x over previous
//
#include <hip/hip_runtime.h>
#include <stdint.h>

// LocallyConnected2D: out[b,f,or,oc] = relu( sum_{c,kh,kw} x[b,c,2or+kh,2oc+kw]*W[f,c,2or+kh,2oc+kw] + bias )
// bias raw-reshape: bias_flat[f*OR*OC + or*OC + oc]
//
// B=32 C=32 H=128 W=128 F=64 OR=OC=64. ~236 MB ideal -> ~37 us HBM floor.
// R5 restructure vs R4 (125 us/dispatch, nothing saturated => latency/LDS-serialization bound):
//  - W removed from LDS entirely. Each wave owns f=fg*4..+3; its W fragments are loaded
//    global->VGPR directly. The 8 bg-lanes request the same 16B (wave-level dup) -> the
//    coalescer merges to one 128-B line per request; every W line still fetched exactly once
//    per kernel. Kills the wa broadcast ds_reads (half of all LDS traffic) and 2/3 of the
//    global_load_lds staging.
//  - LDS 96->64 KB (Xs only), CB 2->4: 8 chunks, ONE __syncthreads per chunk. Staging for
//    chunk it+1 issued at the TOP of iter it (overlaps full compute phase); the barrier's
//    implicit vmcnt(0) drain is ~free since data-dep waits already drained the queue.
//  - Explicit 2-deep register ping-pong (xa[2][4] LDS frags, wb[2][4] global W frags),
//    statically indexed under full s-unroll: forces ~115 live VGPRs so the compiler cannot
//    re-serialize fragment loads (R4's VGPR_Count=64 left zero headroom -> load/use chains).

#define CC  32
#define HH  128
#define WWD 128
#define FF  64
#define ORR 64
#define OCC 64
#define CB  4            // channels per chunk
#define NIT (CC / CB)    // 8
#define CSTRIDE (CB * HH * WWD)   // 65536 floats per chunk advance (4 channels)

#define XBUF 8192        // CB*2kh*32b*32w floats = 32 KB per buffer

__global__ __launch_bounds__(1024, 4) void lc2d_kernel(
    const float* __restrict__ x, const float* __restrict__ wgt,
    const float* __restrict__ bias, float* __restrict__ out)
{
    __shared__ __align__(16) float Xs[2][XBUF];   // 64 KB total

    const int tid = threadIdx.x;
    const int id  = blockIdx.x;
    // oc-pairs sharing 128-B output lines get ids differing by 128 (same id%8 ->
    // same XCD) so L2 merges their half-line writes.
    const int oct = ((id & 1) << 1) | (id >> 7);   // 0..3 -> oc0 = oct*16
    const int orr = (id >> 1) & 63;
    const int w0  = oct * 32;                       // 32 w-floats = 128 B aligned
    const int h0  = orr * 2;

    const int lane = tid & 63;
    const int wv   = tid >> 6;        // wave id 0..15
    const int chk  = lane & 7;        // 16-B chunk within a 128-B global row
    const int sub  = lane >> 3;       // sub-row within this wave's slot

    // ---- x staging pointers. LDS row r in [0,256): r = s*32 + b, s = ci*2+kh.
    // wave wv stages rows wv*8+sub (j=0) and 128+wv*8+sub (j=1).
    const int r0 = wv * 8 + sub;
    const int r1 = 128 + wv * 8 + sub;
    const float* gx0 = x + (((((r0 & 31) * CC) + (r0 >> 6)) * HH) + h0 + ((r0 >> 5) & 1)) * WWD + w0 + chk * 4;
    const float* gx1 = x + (((((r1 & 31) * CC) + (r1 >> 6)) * HH) + h0 + ((r1 >> 5) & 1)) * WWD + w0 + chk * 4;

    auto issue = [&](int p) {
        __builtin_amdgcn_global_load_lds(
            (const __attribute__((address_space(1))) void*)gx0,
            (__attribute__((address_space(3))) void*)(&Xs[p][wv * 256]), 16, 0, 0);
        __builtin_amdgcn_global_load_lds(
            (const __attribute__((address_space(1))) void*)gx1,
            (__attribute__((address_space(3))) void*)(&Xs[p][4096 + wv * 256]), 16, 0, 0);
        gx0 += CSTRIDE; gx1 += CSTRIDE;
    };

    // ---- compute thread mapping: ocg = w 4-chunk (2 oc), bg -> 4 b, fg(=wave) -> 4 f
    const int ocg = tid & 7;
    const int bg  = (tid >> 3) & 7;
    const int fg  = wv;
    const int xoff = bg * 128 + ocg * 4;   // (bg*4)*32 + ocg*4

    // W fragment base pointers for f = fg*4+q (per-chunk advance by CSTRIDE).
    // Per (s,q) load: 8 ocg-lanes x 16 B = one 128-B line, duplicated across 8 bg-lanes
    // (coalescer merges same-address lanes -> one fetch).
    const float* wq0 = wgt + ((fg * 4 + 0) * CC * HH + h0) * WWD + w0 + ocg * 4;
    const float* wq1 = wq0 + CC * HH * WWD;
    const float* wq2 = wq1 + CC * HH * WWD;
    const float* wq3 = wq2 + CC * HH * WWD;

    float acc0[4][4], acc1[4][4];          // [i=b][q=f], oc even / oc odd
#pragma unroll
    for (int i = 0; i < 4; ++i)
#pragma unroll
        for (int q = 0; q < 4; ++q) { acc0[i][q] = 0.f; acc1[i][q] = 0.f; }

    // prologue: chunk 0 staged, then barrier (implicit vmcnt(0) drain makes it visible)
    issue(0);
    __syncthreads();

    for (int it = 0; it < NIT; ++it) {
        const int p = it & 1;
        if (it + 1 < NIT) issue(p ^ 1);   // overlaps the whole compute phase below

        const float* Xp = Xs[p];
        float4 xa[2][4], wb[2][4];
        // preload s = 0 (ci=0, kh=0)
        {
            const float4* xr = (const float4*)(Xp + xoff);
#pragma unroll
            for (int i = 0; i < 4; ++i) xa[0][i] = xr[i * 8];   // b = bg*4 + i
            wb[0][0] = *(const float4*)(wq0);
            wb[0][1] = *(const float4*)(wq1);
            wb[0][2] = *(const float4*)(wq2);
            wb[0][3] = *(const float4*)(wq3);
        }
#pragma unroll
        for (int s = 0; s < 2 * CB; ++s) {       // s = ci*2 + kh, fully unrolled
            const int cur = s & 1, nxt = cur ^ 1;
            if (s + 1 < 2 * CB) {
                const int sn  = s + 1;
                const int off = ((sn >> 1) * HH + (sn & 1)) * WWD;   // compile-time
                const float4* xr = (const float4*)(Xp + sn * 1024 + xoff);
#pragma unroll
                for (int i = 0; i < 4; ++i) xa[nxt][i] = xr[i * 8];
                wb[nxt][0] = *(const float4*)(wq0 + off);
                wb[nxt][1] = *(const float4*)(wq1 + off);
                wb[nxt][2] = *(const float4*)(wq2 + off);
                wb[nxt][3] = *(const float4*)(wq3 + off);
            }
#pragma unroll
            for (int i = 0; i < 4; ++i)
#pragma unroll
                for (int q = 0; q < 4; ++q) {
                    acc0[i][q] = fmaf(xa[cur][i].x, wb[cur][q].x, acc0[i][q]);
                    acc0[i][q] = fmaf(xa[cur][i].y, wb[cur][q].y, acc0[i][q]);
                    acc1[i][q] = fmaf(xa[cur][i].z, wb[cur][q].z, acc1[i][q]);
                    acc1[i][q] = fmaf(xa[cur][i].w, wb[cur][q].w, acc1[i][q]);
                }
        }
        wq0 += CSTRIDE; wq1 += CSTRIDE; wq2 += CSTRIDE; wq3 += CSTRIDE;
        // one barrier per chunk: readers of Xs[p] are done (data-dep drained),
        // staging of chunk it+1 (issued above) completes in-order before the drain.
        __syncthreads();
    }

    // ---- epilogue: bias (raw reshape [F][OR][OC]) + relu, float2 per (b,f)
    const int oc0 = oct * 16 + ocg * 2;
#pragma unroll
    for (int q = 0; q < 4; ++q) {
        const int f = fg * 4 + q;
        const float2 bv = *(const float2*)(bias + f * (ORR * OCC) + orr * OCC + oc0);
#pragma unroll
        for (int i = 0; i < 4; ++i) {
            const int b = bg * 4 + i;
            float2 o;
            o.x = fmaxf(acc0[i][q] + bv.x, 0.f);
            o.y = fmaxf(acc1[i][q] + bv.y, 0.f);
            *(float2*)(out + (((b * FF + f) * ORR + orr) * OCC) + oc0) = o;
        }
    }
}

extern "C" void kernel_launch(void* const* d_in, const int* in_sizes, int n_in,
                              void* d_out, int out_size, void* d_ws, size_t ws_size,
                              hipStream_t stream) {
    (void)in_sizes; (void)n_in; (void)d_ws; (void)ws_size; (void)out_size;
    const float* x    = (const float*)d_in[0];
    const float* wgt  = (const float*)d_in[1];
    const float* bias = (const float*)d_in[2];
    float* out        = (float*)d_out;
    lc2d_kernel<<<dim3(256, 1, 1), dim3(1024, 1, 1), 0, stream>>>(x, wgt, bias, out);
}